// Round 1
// baseline (1435.503 us; speedup 1.0000x reference)
//
#include <hip/hip_runtime.h>
#include <hip/hip_bf16.h>
#include <math.h>

#define TB    4096
#define TSEQ  320
#define NEEG  64
#define NTH   32
#define NH    16
#define NGEO  18
#define TILE_T 56
#define NTILES 6
#define XROWS 68

// d_ws float offsets (prep-kernel output)
#define OFF_W1T  0
#define SZ_W1T   (NEEG*5*NTH)            // 10240
#define OFF_B1F  (OFF_W1T + SZ_W1T)      // 10240
#define OFF_W2T  (OFF_B1F + NTH)         // 10272
#define SZ_W2T   (NTH*3*NH)              // 1536
#define OFF_B2F  (OFF_W2T + SZ_W2T)      // 11808
#define OFF_GWT  (OFF_B2F + NH)          // 11824
#define OFF_FC1T (OFF_GWT + NGEO*NH)     // 12112
#define OFF_FC2T (OFF_FC1T + 160*64)     // 22352  (total 22608 floats)

__global__ void __launch_bounds__(256)
prep_kernel(const float* __restrict__ c1w, const float* __restrict__ c1b,
            const float* __restrict__ s1,  const float* __restrict__ bb1,
            const float* __restrict__ mm1, const float* __restrict__ vv1,
            const float* __restrict__ c2w, const float* __restrict__ c2b,
            const float* __restrict__ s2,  const float* __restrict__ bb2,
            const float* __restrict__ mm2, const float* __restrict__ vv2,
            const float* __restrict__ gw,  const float* __restrict__ fc1w,
            const float* __restrict__ fc2w, float* __restrict__ ws)
{
    const int tid = threadIdx.x;
    // conv1 weights, BN1 folded, layout [i][k][c]
    for (int d = tid; d < SZ_W1T; d += 256) {
        int i = d / 160, r = d - i*160;
        int k = r / 32, c = r - k*32;
        float inv = s1[c] / sqrtf(vv1[c] + 1e-5f);
        ws[OFF_W1T + d] = c1w[c*320 + i*5 + k] * inv;
    }
    if (tid < NTH) {
        float inv = s1[tid] / sqrtf(vv1[tid] + 1e-5f);
        ws[OFF_B1F + tid] = c1b[tid]*inv + bb1[tid] - mm1[tid]*inv;
    }
    // conv2 weights, BN2 folded, layout [c][k][o]
    for (int d = tid; d < SZ_W2T; d += 256) {
        int c = d / 48, r = d - c*48;
        int k = r / 16, o = r - k*16;
        float inv = s2[o] / sqrtf(vv2[o] + 1e-5f);
        ws[OFF_W2T + d] = c2w[o*96 + c*3 + k] * inv;
    }
    if (tid < NH) {
        float inv = s2[tid] / sqrtf(vv2[tid] + 1e-5f);
        ws[OFF_B2F + tid] = c2b[tid]*inv + bb2[tid] - mm2[tid]*inv;
    }
    // geo_w transposed [i][h]
    for (int d = tid; d < NGEO*NH; d += 256) {
        int i = d / NH, h = d - i*NH;
        ws[OFF_GWT + d] = gw[h*NGEO + i];
    }
    // fc1 transposed [f][o]
    for (int d = tid; d < 160*64; d += 256) {
        int f = d / 64, o = d - f*64;
        ws[OFF_FC1T + d] = fc1w[o*160 + f];
    }
    // fc2 transposed [j][o]
    if (tid < 256) {
        int j = tid / 4, o = tid - j*4;
        ws[OFF_FC2T + tid] = fc2w[o*64 + j];
    }
}

__global__ void __launch_bounds__(256, 4)
snn_main(const float* __restrict__ xeeg, const float* __restrict__ xgeo,
         const float* __restrict__ ws,   const float* __restrict__ geo_b,
         const float* __restrict__ gamma, const float* __restrict__ fc1_b,
         const float* __restrict__ fc2_b, float* __restrict__ out)
{
    __shared__ __align__(16) float xT[NEEG][XROWS];   // transposed x tile
    __shared__ __align__(16) float h1T[NTH][64];      // h1 shifted: s=0 <-> t=t0-1
    __shared__ __align__(16) float h2s[64][NH];
    __shared__ __align__(16) float gms[64][NH];
    __shared__ float xg[TILE_T][NGEO];
    __shared__ float gws[NGEO*NH];
    __shared__ float dp[160];
    __shared__ float mid1[64];

    const float* __restrict__ w1t = ws + OFF_W1T;
    const float* __restrict__ b1f = ws + OFF_B1F;
    const float* __restrict__ w2t = ws + OFF_W2T;
    const float* __restrict__ b2f = ws + OFF_B2F;

    const int b = blockIdx.x, tid = threadIdx.x;

    for (int p = tid; p < NGEO*NH; p += 256) gws[p] = ws[OFF_GWT + p];

    // ALIF scan state (threads 0..15, one per hidden channel)
    float eta = 0.f, memv = 0.f, li = 0.f, ps = 0.f, accF = 0.f, accS = 0.f;
    float gam = 0.f;
    if (tid < NH) gam = gamma[tid];

    const int tq  = tid & 15, cq  = tid >> 4;   // conv1 mapping
    const int r0a = tq * 4,   c0  = cq * 2;
    const int oq  = tid & 15, tq2 = tid >> 4;   // conv2 mapping

    for (int j = 0; j < NTILES; ++j) {
        const int t0 = j * TILE_T;
        __syncthreads();   // prior tile's scan must finish before restaging

        // ---- stage x (transposed) : rx in [0,68) <-> t = t0-6+rx ----
        {
            const int i = tid & 63, rbase = tid >> 6;
            const float* xb = xeeg + (size_t)b * TSEQ * NEEG + i;
            #pragma unroll
            for (int p = 0; p < 17; ++p) {
                int rx = rbase + p * 4;
                int tg = t0 - 6 + rx;
                xT[i][rx] = (tg >= 0 && tg < TSEQ) ? xb[tg * NEEG] : 0.f;
            }
        }
        // ---- stage x_geo ----
        for (int p = tid; p < TILE_T * NGEO; p += 256) {
            int r = p / NGEO, ii = p - r * NGEO;
            int tg = t0 + r;
            xg[r][ii] = (tg < TSEQ) ? xgeo[((size_t)b * TSEQ + tg) * NGEO + ii] : 0.f;
        }
        __syncthreads();

        // ---- conv1 + BN1 + ReLU : outputs r1 in [0,64) <-> t = t0-4+r1 ----
        {
            float acc[4][2];
            const float bbv0 = b1f[c0], bbv1 = b1f[c0 + 1];
            #pragma unroll
            for (int t = 0; t < 4; ++t) { acc[t][0] = bbv0; acc[t][1] = bbv1; }
            for (int i = 0; i < NEEG; ++i) {
                float xr[8];
                *reinterpret_cast<float4*>(&xr[0]) = *reinterpret_cast<const float4*>(&xT[i][r0a]);
                *reinterpret_cast<float4*>(&xr[4]) = *reinterpret_cast<const float4*>(&xT[i][r0a + 4]);
                #pragma unroll
                for (int k = 0; k < 5; ++k) {
                    float2 w = *reinterpret_cast<const float2*>(&w1t[(i * 5 + k) * NTH + c0]);
                    #pragma unroll
                    for (int t = 0; t < 4; ++t) {
                        acc[t][0] = fmaf(xr[t + k], w.x, acc[t][0]);
                        acc[t][1] = fmaf(xr[t + k], w.y, acc[t][1]);
                    }
                }
            }
            // write shifted h1; zero outside the valid sequence (conv2 zero-pad!)
            #pragma unroll
            for (int t = 0; t < 4; ++t) {
                int r1 = r0a + t, s = r1 - 3;
                int tg = t0 - 4 + r1;
                if (s >= 0 && s < 58) {
                    bool v = (tg >= 0 && tg < TSEQ);
                    h1T[c0][s]     = v ? fmaxf(acc[t][0], 0.f) : 0.f;
                    h1T[c0 + 1][s] = v ? fmaxf(acc[t][1], 0.f) : 0.f;
                }
            }
        }
        __syncthreads();

        // ---- conv2 + BN2 + ReLU : outputs tt in [0,56), reads h1T[s=tt+k] ----
        if (tq2 < 14) {
            const int r0 = tq2 * 4;
            float acc2[4];
            const float bbv = b2f[oq];
            #pragma unroll
            for (int t = 0; t < 4; ++t) acc2[t] = bbv;
            for (int c = 0; c < NTH; ++c) {
                float hr[8];
                *reinterpret_cast<float4*>(&hr[0]) = *reinterpret_cast<const float4*>(&h1T[c][r0]);
                *reinterpret_cast<float4*>(&hr[4]) = *reinterpret_cast<const float4*>(&h1T[c][r0 + 4]);
                #pragma unroll
                for (int k = 0; k < 3; ++k) {
                    float wv = w2t[(c * 3 + k) * NH + oq];
                    #pragma unroll
                    for (int t = 0; t < 4; ++t) acc2[t] = fmaf(hr[t + k], wv, acc2[t]);
                }
            }
            #pragma unroll
            for (int t = 0; t < 4; ++t) h2s[r0 + t][oq] = fmaxf(acc2[t], 0.f);
        }
        // ---- geo modulation: sigmoid(x_geo @ geo_w^T + b) ----
        for (int p = tid; p < TILE_T * NH; p += 256) {
            int r = p >> 4, hh = p & 15;
            float z = geo_b[hh];
            #pragma unroll
            for (int ii = 0; ii < NGEO; ++ii) z = fmaf(xg[r][ii], gws[ii * NH + hh], z);
            gms[r][hh] = 1.f / (1.f + expf(-z));
        }
        __syncthreads();

        // ---- ALIF scan (sequential over t, one lane per h) ----
        if (tid < NH) {
            int nt = TSEQ - t0; if (nt > TILE_T) nt = TILE_T;
            for (int tt = 0; tt < nt; ++tt) {
                int t = t0 + tt;
                float e = h2s[tt][tid];
                float g = gms[tt][tid];
                eta = 0.36f * eta + 0.64f * ps;
                float theta = 0.5f + 1.8f * eta - gam * g;
                memv = 0.8f * memv + e;
                float spk = (memv - theta >= 0.f) ? 1.f : 0.f;
                memv *= (1.f - spk);
                li = 0.9f * li + spk;
                ps = spk;
                if (((t >> 4) & 1) == 0) accF += li; else accS += li;
                if ((t & 31) == 31) {
                    dp[tid * 10 + (t >> 5)] = (accS - accF) * 0.0625f;
                    accF = 0.f; accS = 0.f;
                }
            }
        }
    }
    __syncthreads();

    // ---- fc1 + ReLU ----
    if (tid < 64) {
        const float* __restrict__ fc1t = ws + OFF_FC1T;
        float z = fc1_b[tid];
        for (int f = 0; f < 160; ++f) z = fmaf(dp[f], fc1t[f * 64 + tid], z);
        mid1[tid] = fmaxf(z, 0.f);
    }
    __syncthreads();
    // ---- fc2 ----
    if (tid < 4) {
        const float* __restrict__ fc2t = ws + OFF_FC2T;
        float z = fc2_b[tid];
        #pragma unroll
        for (int jj = 0; jj < 64; ++jj) z = fmaf(mid1[jj], fc2t[jj * 4 + tid], z);
        out[b * 4 + tid] = z;
    }
}

extern "C" void kernel_launch(void* const* d_in, const int* in_sizes, int n_in,
                              void* d_out, int out_size, void* d_ws, size_t ws_size,
                              hipStream_t stream)
{
    const float* xeeg = (const float*)d_in[0];
    const float* xgeo = (const float*)d_in[1];
    const float* c1w  = (const float*)d_in[2];
    const float* c1b  = (const float*)d_in[3];
    const float* s1   = (const float*)d_in[4];
    const float* bb1  = (const float*)d_in[5];
    const float* mm1  = (const float*)d_in[6];
    const float* vv1  = (const float*)d_in[7];
    const float* c2w  = (const float*)d_in[8];
    const float* c2b  = (const float*)d_in[9];
    const float* s2   = (const float*)d_in[10];
    const float* bb2  = (const float*)d_in[11];
    const float* mm2  = (const float*)d_in[12];
    const float* vv2  = (const float*)d_in[13];
    const float* gw   = (const float*)d_in[14];
    const float* gb   = (const float*)d_in[15];
    const float* gam  = (const float*)d_in[16];
    const float* fc1w = (const float*)d_in[17];
    const float* fc1b = (const float*)d_in[18];
    const float* fc2w = (const float*)d_in[19];
    const float* fc2b = (const float*)d_in[20];
    float* ws   = (float*)d_ws;
    float* outp = (float*)d_out;

    hipLaunchKernelGGL(prep_kernel, dim3(1), dim3(256), 0, stream,
                       c1w, c1b, s1, bb1, mm1, vv1, c2w, c2b, s2, bb2, mm2, vv2,
                       gw, fc1w, fc2w, ws);
    hipLaunchKernelGGL(snn_main, dim3(TB), dim3(256), 0, stream,
                       xeeg, xgeo, ws, gb, gam, fc1b, fc2b, outp);
}

// Round 3
// 1133.859 us; speedup vs baseline: 1.2660x; 1.2660x over previous
//
#include <hip/hip_runtime.h>
#include <hip/hip_bf16.h>
#include <math.h>

#define TB    4096
#define TSEQ  320
#define NEEG  64
#define NTH   32
#define NH    16
#define NGEO  18
#define TILE_T 56
#define NTILES 6
#define XROWS 68

// d_ws float offsets
#define OFF_W1T  0
#define SZ_W1T   (NEEG*5*NTH)            // 10240
#define OFF_B1F  (OFF_W1T + SZ_W1T)      // 10240
#define OFF_W2T  (OFF_B1F + NTH)         // 10272
#define SZ_W2T   (NTH*3*NH)              // 1536
#define OFF_B2F  (OFF_W2T + SZ_W2T)      // 11808
#define OFF_GWT  (OFF_B2F + NH)          // 11824
#define OFF_FC1T (OFF_GWT + NGEO*NH)     // 12112
#define OFF_FC2T (OFF_FC1T + 160*64)     // 22352, weights end 22608

// big-scratch regions (floats)
#define OFF_E    32768
#define SZ_EC    (TB*TSEQ*NH)            // 20971520
#define OFF_C    (OFF_E + SZ_EC)         // 21004288
#define OFF_DP   (OFF_C + SZ_EC)         // 41975808
#define SZ_DP    (TB*160)                // 655360
#define REQ_FLOATS ((size_t)OFF_DP + SZ_DP)   // 42631168
#define REQ_BYTES  (REQ_FLOATS * 4)           // 170,524,672

__global__ void __launch_bounds__(256)
prep_kernel(const float* __restrict__ c1w, const float* __restrict__ c1b,
            const float* __restrict__ s1,  const float* __restrict__ bb1,
            const float* __restrict__ mm1, const float* __restrict__ vv1,
            const float* __restrict__ c2w, const float* __restrict__ c2b,
            const float* __restrict__ s2,  const float* __restrict__ bb2,
            const float* __restrict__ mm2, const float* __restrict__ vv2,
            const float* __restrict__ gw,  const float* __restrict__ fc1w,
            const float* __restrict__ fc2w, float* __restrict__ ws)
{
    const int tid = threadIdx.x;
    for (int d = tid; d < SZ_W1T; d += 256) {
        int i = d / 160, r = d - i*160;
        int k = r / 32, c = r - k*32;
        float inv = s1[c] / sqrtf(vv1[c] + 1e-5f);
        ws[OFF_W1T + d] = c1w[c*320 + i*5 + k] * inv;
    }
    if (tid < NTH) {
        float inv = s1[tid] / sqrtf(vv1[tid] + 1e-5f);
        ws[OFF_B1F + tid] = c1b[tid]*inv + bb1[tid] - mm1[tid]*inv;
    }
    for (int d = tid; d < SZ_W2T; d += 256) {
        int c = d / 48, r = d - c*48;
        int k = r / 16, o = r - k*16;
        float inv = s2[o] / sqrtf(vv2[o] + 1e-5f);
        ws[OFF_W2T + d] = c2w[o*96 + c*3 + k] * inv;
    }
    if (tid < NH) {
        float inv = s2[tid] / sqrtf(vv2[tid] + 1e-5f);
        ws[OFF_B2F + tid] = c2b[tid]*inv + bb2[tid] - mm2[tid]*inv;
    }
    for (int d = tid; d < NGEO*NH; d += 256) {
        int i = d / NH, h = d - i*NH;
        ws[OFF_GWT + d] = gw[h*NGEO + i];
    }
    for (int d = tid; d < 160*64; d += 256) {
        int f = d / 64, o = d - f*64;
        ws[OFF_FC1T + d] = fc1w[o*160 + f];
    }
    if (tid < 256) {
        int j = tid / 4, o = tid - j*4;
        ws[OFF_FC2T + tid] = fc2w[o*64 + j];
    }
}

// ---------------- Kernel A: conv1+conv2+geo, one block per (tile, b) ----------------
__global__ void __launch_bounds__(256, 5)
conv_kernel(const float* __restrict__ xeeg, const float* __restrict__ xgeo,
            const float* __restrict__ ws,   const float* __restrict__ geo_b,
            const float* __restrict__ gamma,
            float* __restrict__ E, float* __restrict__ C)
{
    __shared__ __align__(16) float xT[NEEG][XROWS];
    __shared__ __align__(16) float h1T[NTH][64];
    __shared__ float xg[TILE_T][NGEO];
    __shared__ float gws[NGEO*NH];

    const float* __restrict__ w1t = ws + OFF_W1T;
    const float* __restrict__ b1f = ws + OFF_B1F;
    const float* __restrict__ w2t = ws + OFF_W2T;
    const float* __restrict__ b2f = ws + OFF_B2F;

    const int j = blockIdx.x, b = blockIdx.y, tid = threadIdx.x;
    const int t0 = j * TILE_T;

    for (int p = tid; p < NGEO*NH; p += 256) gws[p] = ws[OFF_GWT + p];

    // ---- stage x (transposed) ----
    {
        const int i = tid & 63, rbase = tid >> 6;
        const float* xb = xeeg + (size_t)b * TSEQ * NEEG + i;
        #pragma unroll
        for (int p = 0; p < 17; ++p) {
            int rx = rbase + p * 4;
            int tg = t0 - 6 + rx;
            xT[i][rx] = (tg >= 0 && tg < TSEQ) ? xb[tg * NEEG] : 0.f;
        }
    }
    for (int p = tid; p < TILE_T * NGEO; p += 256) {
        int r = p / NGEO, ii = p - r * NGEO;
        int tg = t0 + r;
        xg[r][ii] = (tg < TSEQ) ? xgeo[((size_t)b * TSEQ + tg) * NGEO + ii] : 0.f;
    }
    __syncthreads();

    // ---- conv1 + BN1 + ReLU ----
    {
        const int tq = tid & 15, cq = tid >> 4;
        const int r0a = tq * 4, c0 = cq * 2;
        float acc[4][2];
        const float bbv0 = b1f[c0], bbv1 = b1f[c0 + 1];
        #pragma unroll
        for (int t = 0; t < 4; ++t) { acc[t][0] = bbv0; acc[t][1] = bbv1; }
        #pragma unroll 2
        for (int i = 0; i < NEEG; ++i) {
            float xr[8];
            *reinterpret_cast<float4*>(&xr[0]) = *reinterpret_cast<const float4*>(&xT[i][r0a]);
            *reinterpret_cast<float4*>(&xr[4]) = *reinterpret_cast<const float4*>(&xT[i][r0a + 4]);
            #pragma unroll
            for (int k = 0; k < 5; ++k) {
                float2 w = *reinterpret_cast<const float2*>(&w1t[(i * 5 + k) * NTH + c0]);
                #pragma unroll
                for (int t = 0; t < 4; ++t) {
                    acc[t][0] = fmaf(xr[t + k], w.x, acc[t][0]);
                    acc[t][1] = fmaf(xr[t + k], w.y, acc[t][1]);
                }
            }
        }
        #pragma unroll
        for (int t = 0; t < 4; ++t) {
            int r1 = r0a + t, s = r1 - 3;
            int tg = t0 - 4 + r1;
            if (s >= 0 && s < 58) {
                bool v = (tg >= 0 && tg < TSEQ);
                h1T[c0][s]     = v ? fmaxf(acc[t][0], 0.f) : 0.f;
                h1T[c0 + 1][s] = v ? fmaxf(acc[t][1], 0.f) : 0.f;
            }
        }
    }
    __syncthreads();

    // ---- conv2 + BN2 + ReLU -> E ----
    {
        const int oq = tid & 15, tq2 = tid >> 4;
        if (tq2 < 14 && (t0 + 4*tq2) < TSEQ) {
            const int r0 = tq2 * 4;
            float acc2[4];
            const float bbv = b2f[oq];
            #pragma unroll
            for (int t = 0; t < 4; ++t) acc2[t] = bbv;
            for (int c = 0; c < NTH; ++c) {
                float hr[8];
                *reinterpret_cast<float4*>(&hr[0]) = *reinterpret_cast<const float4*>(&h1T[c][r0]);
                *reinterpret_cast<float4*>(&hr[4]) = *reinterpret_cast<const float4*>(&h1T[c][r0 + 4]);
                #pragma unroll
                for (int k = 0; k < 3; ++k) {
                    float wv = w2t[(c * 3 + k) * NH + oq];
                    #pragma unroll
                    for (int t = 0; t < 4; ++t) acc2[t] = fmaf(hr[t + k], wv, acc2[t]);
                }
            }
            float4 ev;
            ev.x = fmaxf(acc2[0], 0.f); ev.y = fmaxf(acc2[1], 0.f);
            ev.z = fmaxf(acc2[2], 0.f); ev.w = fmaxf(acc2[3], 0.f);
            size_t t4 = (size_t)(t0 >> 2) + tq2;
            *reinterpret_cast<float4*>(&E[(((size_t)b * 80 + t4) * NH + oq) * 4]) = ev;
        }
    }
    // ---- geo modulation -> C (c = gamma*sigmoid) ----
    {
        const int hh = tid & 15, rq = tid >> 4;
        if (rq < 14 && (t0 + 4*rq) < TSEQ) {
            const float gam = gamma[hh];
            const float gb = geo_b[hh];
            float4 cv;
            float* cvp = reinterpret_cast<float*>(&cv);
            #pragma unroll
            for (int tt = 0; tt < 4; ++tt) {
                int r = rq * 4 + tt;
                float z = gb;
                #pragma unroll
                for (int ii = 0; ii < NGEO; ++ii)
                    z = fmaf(xg[r][ii], gws[ii * NH + hh], z);
                cvp[tt] = gam * (1.f / (1.f + expf(-z)));
            }
            size_t t4 = (size_t)(t0 >> 2) + rq;
            *reinterpret_cast<float4*>(&C[(((size_t)b * 80 + t4) * NH + hh) * 4]) = cv;
        }
    }
}

// ---------------- Kernel B: ALIF scan, one lane per (b,h) ----------------
__global__ void __launch_bounds__(256)
scan_kernel(const float* __restrict__ E, const float* __restrict__ C,
            float* __restrict__ DP)
{
    const int tid = threadIdx.x;
    const int h = tid & 15;
    const int b = blockIdx.x * 16 + (tid >> 4);
    const float4* e4 = reinterpret_cast<const float4*>(E) + ((size_t)b * 80 * NH + h);
    const float4* c4 = reinterpret_cast<const float4*>(C) + ((size_t)b * 80 * NH + h);

    float eta = 0.f, memv = 0.f, li = 0.f, ps = 0.f, accF = 0.f, accS = 0.f;
    float4 ev = e4[0], cv = c4[0];
    for (int t4 = 0; t4 < 80; ++t4) {
        float4 en, cn;
        if (t4 < 79) { en = e4[(size_t)(t4 + 1) * NH]; cn = c4[(size_t)(t4 + 1) * NH]; }
        const float* evp = reinterpret_cast<const float*>(&ev);
        const float* cvp = reinterpret_cast<const float*>(&cv);
        #pragma unroll
        for (int tt = 0; tt < 4; ++tt) {
            float e = evp[tt], c = cvp[tt];
            eta = 0.36f * eta + 0.64f * ps;
            float theta = 0.5f + 1.8f * eta - c;
            memv = 0.8f * memv + e;
            float spk = (memv - theta >= 0.f) ? 1.f : 0.f;
            memv *= (1.f - spk);
            li = 0.9f * li + spk;
            ps = spk;
            int t = t4 * 4 + tt;
            if (((t >> 4) & 1) == 0) accF += li; else accS += li;
        }
        if ((t4 & 7) == 7) {
            DP[(size_t)b * 160 + h * 10 + (t4 >> 3)] = (accS - accF) * 0.0625f;
            accF = 0.f; accS = 0.f;
        }
        ev = en; cv = cn;
    }
}

// ---------------- Kernel C: fc1+fc2, 4 batch per block ----------------
__global__ void __launch_bounds__(256)
fc_kernel(const float* __restrict__ DP, const float* __restrict__ ws,
          const float* __restrict__ fc1_b, const float* __restrict__ fc2_b,
          float* __restrict__ out)
{
    __shared__ float sh_dp[4][160];
    __shared__ float mid[4][64];
    const int tid = threadIdx.x;
    const int b0 = blockIdx.x * 4;
    for (int p = tid; p < 640; p += 256) sh_dp[p / 160][p - (p / 160) * 160] = DP[(size_t)b0 * 160 + p];
    __syncthreads();
    {
        const int bl = tid >> 6, o = tid & 63;
        const float* __restrict__ fc1t = ws + OFF_FC1T;
        float z = fc1_b[o];
        for (int f = 0; f < 160; ++f) z = fmaf(sh_dp[bl][f], fc1t[f * 64 + o], z);
        mid[bl][o] = fmaxf(z, 0.f);
    }
    __syncthreads();
    if (tid < 16) {
        const int bl = tid >> 2, oo = tid & 3;
        const float* __restrict__ fc2t = ws + OFF_FC2T;
        float z = fc2_b[oo];
        #pragma unroll
        for (int jj = 0; jj < 64; ++jj) z = fmaf(mid[bl][jj], fc2t[jj * 4 + oo], z);
        out[(size_t)(b0 + bl) * 4 + oo] = z;
    }
}

// ---------------- Fallback: round-1 fused kernel (used if ws too small) ----------------
__global__ void __launch_bounds__(256, 4)
snn_fused(const float* __restrict__ xeeg, const float* __restrict__ xgeo,
          const float* __restrict__ ws,   const float* __restrict__ geo_b,
          const float* __restrict__ gamma, const float* __restrict__ fc1_b,
          const float* __restrict__ fc2_b, float* __restrict__ out)
{
    __shared__ __align__(16) float xT[NEEG][XROWS];
    __shared__ __align__(16) float h1T[NTH][64];
    __shared__ __align__(16) float h2s[64][NH];
    __shared__ __align__(16) float gms[64][NH];
    __shared__ float xg[TILE_T][NGEO];
    __shared__ float gws[NGEO*NH];
    __shared__ float dp[160];
    __shared__ float mid1[64];

    const float* __restrict__ w1t = ws + OFF_W1T;
    const float* __restrict__ b1f = ws + OFF_B1F;
    const float* __restrict__ w2t = ws + OFF_W2T;
    const float* __restrict__ b2f = ws + OFF_B2F;

    const int b = blockIdx.x, tid = threadIdx.x;
    for (int p = tid; p < NGEO*NH; p += 256) gws[p] = ws[OFF_GWT + p];

    float eta = 0.f, memv = 0.f, li = 0.f, ps = 0.f, accF = 0.f, accS = 0.f;
    float gam = 0.f;
    if (tid < NH) gam = gamma[tid];

    const int tq  = tid & 15, cq  = tid >> 4;
    const int r0a = tq * 4,   c0  = cq * 2;
    const int oq  = tid & 15, tq2 = tid >> 4;

    for (int j = 0; j < NTILES; ++j) {
        const int t0 = j * TILE_T;
        __syncthreads();
        {
            const int i = tid & 63, rbase = tid >> 6;
            const float* xb = xeeg + (size_t)b * TSEQ * NEEG + i;
            #pragma unroll
            for (int p = 0; p < 17; ++p) {
                int rx = rbase + p * 4;
                int tg = t0 - 6 + rx;
                xT[i][rx] = (tg >= 0 && tg < TSEQ) ? xb[tg * NEEG] : 0.f;
            }
        }
        for (int p = tid; p < TILE_T * NGEO; p += 256) {
            int r = p / NGEO, ii = p - r * NGEO;
            int tg = t0 + r;
            xg[r][ii] = (tg < TSEQ) ? xgeo[((size_t)b * TSEQ + tg) * NGEO + ii] : 0.f;
        }
        __syncthreads();
        {
            float acc[4][2];
            const float bbv0 = b1f[c0], bbv1 = b1f[c0 + 1];
            #pragma unroll
            for (int t = 0; t < 4; ++t) { acc[t][0] = bbv0; acc[t][1] = bbv1; }
            for (int i = 0; i < NEEG; ++i) {
                float xr[8];
                *reinterpret_cast<float4*>(&xr[0]) = *reinterpret_cast<const float4*>(&xT[i][r0a]);
                *reinterpret_cast<float4*>(&xr[4]) = *reinterpret_cast<const float4*>(&xT[i][r0a + 4]);
                #pragma unroll
                for (int k = 0; k < 5; ++k) {
                    float2 w = *reinterpret_cast<const float2*>(&w1t[(i * 5 + k) * NTH + c0]);
                    #pragma unroll
                    for (int t = 0; t < 4; ++t) {
                        acc[t][0] = fmaf(xr[t + k], w.x, acc[t][0]);
                        acc[t][1] = fmaf(xr[t + k], w.y, acc[t][1]);
                    }
                }
            }
            #pragma unroll
            for (int t = 0; t < 4; ++t) {
                int r1 = r0a + t, s = r1 - 3;
                int tg = t0 - 4 + r1;
                if (s >= 0 && s < 58) {
                    bool v = (tg >= 0 && tg < TSEQ);
                    h1T[c0][s]     = v ? fmaxf(acc[t][0], 0.f) : 0.f;
                    h1T[c0 + 1][s] = v ? fmaxf(acc[t][1], 0.f) : 0.f;
                }
            }
        }
        __syncthreads();
        if (tq2 < 14) {
            const int r0 = tq2 * 4;
            float acc2[4];
            const float bbv = b2f[oq];
            #pragma unroll
            for (int t = 0; t < 4; ++t) acc2[t] = bbv;
            for (int c = 0; c < NTH; ++c) {
                float hr[8];
                *reinterpret_cast<float4*>(&hr[0]) = *reinterpret_cast<const float4*>(&h1T[c][r0]);
                *reinterpret_cast<float4*>(&hr[4]) = *reinterpret_cast<const float4*>(&h1T[c][r0 + 4]);
                #pragma unroll
                for (int k = 0; k < 3; ++k) {
                    float wv = w2t[(c * 3 + k) * NH + oq];
                    #pragma unroll
                    for (int t = 0; t < 4; ++t) acc2[t] = fmaf(hr[t + k], wv, acc2[t]);
                }
            }
            #pragma unroll
            for (int t = 0; t < 4; ++t) h2s[r0 + t][oq] = fmaxf(acc2[t], 0.f);
        }
        for (int p = tid; p < TILE_T * NH; p += 256) {
            int r = p >> 4, hh = p & 15;
            float z = geo_b[hh];
            #pragma unroll
            for (int ii = 0; ii < NGEO; ++ii) z = fmaf(xg[r][ii], gws[ii * NH + hh], z);
            gms[r][hh] = 1.f / (1.f + expf(-z));
        }
        __syncthreads();
        if (tid < NH) {
            int nt = TSEQ - t0; if (nt > TILE_T) nt = TILE_T;
            for (int tt = 0; tt < nt; ++tt) {
                int t = t0 + tt;
                float e = h2s[tt][tid];
                float g = gms[tt][tid];
                eta = 0.36f * eta + 0.64f * ps;
                float theta = 0.5f + 1.8f * eta - gam * g;
                memv = 0.8f * memv + e;
                float spk = (memv - theta >= 0.f) ? 1.f : 0.f;
                memv *= (1.f - spk);
                li = 0.9f * li + spk;
                ps = spk;
                if (((t >> 4) & 1) == 0) accF += li; else accS += li;
                if ((t & 31) == 31) {
                    dp[tid * 10 + (t >> 5)] = (accS - accF) * 0.0625f;
                    accF = 0.f; accS = 0.f;
                }
            }
        }
    }
    __syncthreads();
    if (tid < 64) {
        const float* __restrict__ fc1t = ws + OFF_FC1T;
        float z = fc1_b[tid];
        for (int f = 0; f < 160; ++f) z = fmaf(dp[f], fc1t[f * 64 + tid], z);
        mid1[tid] = fmaxf(z, 0.f);
    }
    __syncthreads();
    if (tid < 4) {
        const float* __restrict__ fc2t = ws + OFF_FC2T;
        float z = fc2_b[tid];
        #pragma unroll
        for (int jj = 0; jj < 64; ++jj) z = fmaf(mid1[jj], fc2t[jj * 4 + tid], z);
        out[b * 4 + tid] = z;
    }
}

extern "C" void kernel_launch(void* const* d_in, const int* in_sizes, int n_in,
                              void* d_out, int out_size, void* d_ws, size_t ws_size,
                              hipStream_t stream)
{
    const float* xeeg = (const float*)d_in[0];
    const float* xgeo = (const float*)d_in[1];
    const float* c1w  = (const float*)d_in[2];
    const float* c1b  = (const float*)d_in[3];
    const float* s1   = (const float*)d_in[4];
    const float* bb1  = (const float*)d_in[5];
    const float* mm1  = (const float*)d_in[6];
    const float* vv1  = (const float*)d_in[7];
    const float* c2w  = (const float*)d_in[8];
    const float* c2b  = (const float*)d_in[9];
    const float* s2   = (const float*)d_in[10];
    const float* bb2  = (const float*)d_in[11];
    const float* mm2  = (const float*)d_in[12];
    const float* vv2  = (const float*)d_in[13];
    const float* gw   = (const float*)d_in[14];
    const float* gb   = (const float*)d_in[15];
    const float* gam  = (const float*)d_in[16];
    const float* fc1w = (const float*)d_in[17];
    const float* fc1b = (const float*)d_in[18];
    const float* fc2w = (const float*)d_in[19];
    const float* fc2b = (const float*)d_in[20];
    float* ws   = (float*)d_ws;
    float* outp = (float*)d_out;

    hipLaunchKernelGGL(prep_kernel, dim3(1), dim3(256), 0, stream,
                       c1w, c1b, s1, bb1, mm1, vv1, c2w, c2b, s2, bb2, mm2, vv2,
                       gw, fc1w, fc2w, ws);

    if (ws_size >= REQ_BYTES) {
        float* E  = ws + OFF_E;
        float* C  = ws + OFF_C;
        float* DP = ws + OFF_DP;
        hipLaunchKernelGGL(conv_kernel, dim3(NTILES, TB), dim3(256), 0, stream,
                           xeeg, xgeo, ws, gb, gam, E, C);
        hipLaunchKernelGGL(scan_kernel, dim3(TB / 16), dim3(256), 0, stream,
                           E, C, DP);
        hipLaunchKernelGGL(fc_kernel, dim3(TB / 4), dim3(256), 0, stream,
                           DP, ws, fc1b, fc2b, outp);
    } else {
        hipLaunchKernelGGL(snn_fused, dim3(TB), dim3(256), 0, stream,
                           xeeg, xgeo, ws, gb, gam, fc1b, fc2b, outp);
    }
}

// Round 4
// 895.399 us; speedup vs baseline: 1.6032x; 1.2663x over previous
//
#include <hip/hip_runtime.h>
#include <hip/hip_bf16.h>
#include <math.h>

#define TB    4096
#define TSEQ  320
#define NEEG  64
#define NTH   32
#define NH    16
#define NGEO  18
#define TILE_T 56
#define NTILES 6
#define XROWS 68

// d_ws float offsets
#define OFF_W1T  0
#define SZ_W1T   (NEEG*5*NTH)            // 10240
#define OFF_B1F  (OFF_W1T + SZ_W1T)      // 10240
#define OFF_W2T  (OFF_B1F + NTH)         // 10272
#define SZ_W2T   (NTH*3*NH)              // 1536
#define OFF_B2F  (OFF_W2T + SZ_W2T)      // 11808
#define OFF_GWT  (OFF_B2F + NH)          // 11824
#define OFF_FC1T (OFF_GWT + NGEO*NH)     // 12112
#define OFF_FC2T (OFF_FC1T + 160*64)     // 22352, weights end 22608

// big-scratch regions (floats)
#define OFF_E    32768
#define SZ_EC    (TB*TSEQ*NH)            // 20971520
#define OFF_C    (OFF_E + SZ_EC)         // 21004288
#define OFF_DP   (OFF_C + SZ_EC)         // 41975808
#define SZ_DP    (TB*160)                // 655360
#define REQ_FLOATS ((size_t)OFF_DP + SZ_DP)   // 42631168
#define REQ_BYTES  (REQ_FLOATS * 4)           // 170,524,672

__global__ void __launch_bounds__(256)
prep_kernel(const float* __restrict__ c1w, const float* __restrict__ c1b,
            const float* __restrict__ s1,  const float* __restrict__ bb1,
            const float* __restrict__ mm1, const float* __restrict__ vv1,
            const float* __restrict__ c2w, const float* __restrict__ c2b,
            const float* __restrict__ s2,  const float* __restrict__ bb2,
            const float* __restrict__ mm2, const float* __restrict__ vv2,
            const float* __restrict__ gw,  const float* __restrict__ fc1w,
            const float* __restrict__ fc2w, float* __restrict__ ws)
{
    const int tid = threadIdx.x;
    for (int d = tid; d < SZ_W1T; d += 256) {
        int i = d / 160, r = d - i*160;
        int k = r / 32, c = r - k*32;
        float inv = s1[c] / sqrtf(vv1[c] + 1e-5f);
        ws[OFF_W1T + d] = c1w[c*320 + i*5 + k] * inv;
    }
    if (tid < NTH) {
        float inv = s1[tid] / sqrtf(vv1[tid] + 1e-5f);
        ws[OFF_B1F + tid] = c1b[tid]*inv + bb1[tid] - mm1[tid]*inv;
    }
    for (int d = tid; d < SZ_W2T; d += 256) {
        int c = d / 48, r = d - c*48;
        int k = r / 16, o = r - k*16;
        float inv = s2[o] / sqrtf(vv2[o] + 1e-5f);
        ws[OFF_W2T + d] = c2w[o*96 + c*3 + k] * inv;
    }
    if (tid < NH) {
        float inv = s2[tid] / sqrtf(vv2[tid] + 1e-5f);
        ws[OFF_B2F + tid] = c2b[tid]*inv + bb2[tid] - mm2[tid]*inv;
    }
    for (int d = tid; d < NGEO*NH; d += 256) {
        int i = d / NH, h = d - i*NH;
        ws[OFF_GWT + d] = gw[h*NGEO + i];
    }
    for (int d = tid; d < 160*64; d += 256) {
        int f = d / 64, o = d - f*64;
        ws[OFF_FC1T + d] = fc1w[o*160 + f];
    }
    if (tid < 256) {
        int j = tid / 4, o = tid - j*4;
        ws[OFF_FC2T + tid] = fc2w[o*64 + j];
    }
}

// ---------------- Kernel A: conv1+conv2+geo, one block per batch element ----------------
// Weights LDS-resident (staged once); 6 t-tiles processed in-block.
__global__ void __launch_bounds__(256, 2)
convb_kernel(const float* __restrict__ xeeg, const float* __restrict__ xgeo,
             const float* __restrict__ ws,   const float* __restrict__ geo_b,
             const float* __restrict__ gamma,
             float* __restrict__ E, float* __restrict__ C)
{
    __shared__ __align__(16) float w1s[SZ_W1T];       // 40960 B, layout [i][k][c]
    __shared__ __align__(16) float w2s[SZ_W2T];       // 6144 B,  layout [c][k][o]
    __shared__ __align__(16) float xT[NEEG][XROWS];   // 17408 B
    __shared__ __align__(16) float h1T[NTH][64];      // 8192 B
    __shared__ float xg[TILE_T][NGEO];                // 4032 B
    __shared__ float gws[NGEO*NH];                    // 1152 B
    __shared__ float b1s[NTH], b2s[NH], gbs[NH], gams[NH];
    // total ~76.4 KB -> 2 blocks/CU

    const int b = blockIdx.x, tid = threadIdx.x;

    // ---- stage weights once (coalesced float4) ----
    for (int p = tid; p < SZ_W1T/4; p += 256)
        reinterpret_cast<float4*>(w1s)[p] = reinterpret_cast<const float4*>(ws + OFF_W1T)[p];
    for (int p = tid; p < SZ_W2T/4; p += 256)
        reinterpret_cast<float4*>(w2s)[p] = reinterpret_cast<const float4*>(ws + OFF_W2T)[p];
    if (tid < NTH) b1s[tid] = ws[OFF_B1F + tid];
    if (tid < NH) { b2s[tid] = ws[OFF_B2F + tid]; gbs[tid] = geo_b[tid]; gams[tid] = gamma[tid]; }
    for (int p = tid; p < NGEO*NH; p += 256) gws[p] = ws[OFF_GWT + p];

    const int tq = tid & 15, cq = tid >> 4;
    const int r0a = tq * 4,  c0 = cq * 2;
    const int oq = tid & 15, tq2 = tid >> 4;

    for (int j = 0; j < NTILES; ++j) {
        const int t0 = j * TILE_T;
        __syncthreads();   // prev tile's conv2/geo done (and weight staging on j==0 partly)

        // ---- stage x (transposed): rx in [0,68) <-> t = t0-6+rx ----
        {
            const int i = tid & 63, rbase = tid >> 6;
            const float* xb = xeeg + (size_t)b * TSEQ * NEEG + i;
            #pragma unroll
            for (int p = 0; p < 17; ++p) {
                int rx = rbase + p * 4;
                int tg = t0 - 6 + rx;
                xT[i][rx] = (tg >= 0 && tg < TSEQ) ? xb[tg * NEEG] : 0.f;
            }
        }
        for (int p = tid; p < TILE_T * NGEO; p += 256) {
            int r = p / NGEO, ii = p - r * NGEO;
            int tg = t0 + r;
            xg[r][ii] = (tg < TSEQ) ? xgeo[((size_t)b * TSEQ + tg) * NGEO + ii] : 0.f;
        }
        __syncthreads();   // x staged AND (j==0) weights staged

        // ---- conv1 + BN1 + ReLU : r1 in [0,64) <-> t = t0-4+r1 ----
        {
            float acc[4][2];
            const float bbv0 = b1s[c0], bbv1 = b1s[c0 + 1];
            #pragma unroll
            for (int t = 0; t < 4; ++t) { acc[t][0] = bbv0; acc[t][1] = bbv1; }
            const float* w1p = w1s + c0;
            #pragma unroll 4
            for (int i = 0; i < NEEG; ++i) {
                float xr[8];
                *reinterpret_cast<float4*>(&xr[0]) = *reinterpret_cast<const float4*>(&xT[i][r0a]);
                *reinterpret_cast<float4*>(&xr[4]) = *reinterpret_cast<const float4*>(&xT[i][r0a + 4]);
                #pragma unroll
                for (int k = 0; k < 5; ++k) {
                    float2 w = *reinterpret_cast<const float2*>(&w1p[(i * 5 + k) * NTH]);
                    #pragma unroll
                    for (int t = 0; t < 4; ++t) {
                        acc[t][0] = fmaf(xr[t + k], w.x, acc[t][0]);
                        acc[t][1] = fmaf(xr[t + k], w.y, acc[t][1]);
                    }
                }
            }
            #pragma unroll
            for (int t = 0; t < 4; ++t) {
                int r1 = r0a + t, s = r1 - 3;
                int tg = t0 - 4 + r1;
                if (s >= 0 && s < 58) {
                    bool v = (tg >= 0 && tg < TSEQ);
                    h1T[c0][s]     = v ? fmaxf(acc[t][0], 0.f) : 0.f;
                    h1T[c0 + 1][s] = v ? fmaxf(acc[t][1], 0.f) : 0.f;
                }
            }
        }
        __syncthreads();

        // ---- conv2 + BN2 + ReLU -> E ----
        if (tq2 < 14 && (t0 + 4*tq2) < TSEQ) {
            const int r0 = tq2 * 4;
            float acc2[4];
            const float bbv = b2s[oq];
            #pragma unroll
            for (int t = 0; t < 4; ++t) acc2[t] = bbv;
            const float* w2p = w2s + oq;
            #pragma unroll 4
            for (int c = 0; c < NTH; ++c) {
                float hr[8];
                *reinterpret_cast<float4*>(&hr[0]) = *reinterpret_cast<const float4*>(&h1T[c][r0]);
                *reinterpret_cast<float4*>(&hr[4]) = *reinterpret_cast<const float4*>(&h1T[c][r0 + 4]);
                #pragma unroll
                for (int k = 0; k < 3; ++k) {
                    float wv = w2p[(c * 3 + k) * NH];
                    #pragma unroll
                    for (int t = 0; t < 4; ++t) acc2[t] = fmaf(hr[t + k], wv, acc2[t]);
                }
            }
            float4 ev;
            ev.x = fmaxf(acc2[0], 0.f); ev.y = fmaxf(acc2[1], 0.f);
            ev.z = fmaxf(acc2[2], 0.f); ev.w = fmaxf(acc2[3], 0.f);
            size_t t4 = (size_t)(t0 >> 2) + tq2;
            *reinterpret_cast<float4*>(&E[(((size_t)b * 80 + t4) * NH + oq) * 4]) = ev;
        }
        // ---- geo modulation -> C (c = gamma*sigmoid) ----
        {
            const int hh = tid & 15, rq = tid >> 4;
            if (rq < 14 && (t0 + 4*rq) < TSEQ) {
                const float gam = gams[hh];
                const float gb = gbs[hh];
                float4 cv;
                float* cvp = reinterpret_cast<float*>(&cv);
                #pragma unroll
                for (int tt = 0; tt < 4; ++tt) {
                    int r = rq * 4 + tt;
                    float z = gb;
                    #pragma unroll
                    for (int ii = 0; ii < NGEO; ++ii)
                        z = fmaf(xg[r][ii], gws[ii * NH + hh], z);
                    cvp[tt] = gam * (1.f / (1.f + expf(-z)));
                }
                size_t t4 = (size_t)(t0 >> 2) + rq;
                *reinterpret_cast<float4*>(&C[(((size_t)b * 80 + t4) * NH + hh) * 4]) = cv;
            }
        }
    }
}

// ---------------- Kernel B: ALIF scan, one lane per (b,h) ----------------
__global__ void __launch_bounds__(256)
scan_kernel(const float* __restrict__ E, const float* __restrict__ C,
            float* __restrict__ DP)
{
    const int tid = threadIdx.x;
    const int h = tid & 15;
    const int b = blockIdx.x * 16 + (tid >> 4);
    const float4* e4 = reinterpret_cast<const float4*>(E) + ((size_t)b * 80 * NH + h);
    const float4* c4 = reinterpret_cast<const float4*>(C) + ((size_t)b * 80 * NH + h);

    float eta = 0.f, memv = 0.f, li = 0.f, ps = 0.f, accF = 0.f, accS = 0.f;
    float4 ev = e4[0], cv = c4[0];
    for (int t4 = 0; t4 < 80; ++t4) {
        float4 en, cn;
        if (t4 < 79) { en = e4[(size_t)(t4 + 1) * NH]; cn = c4[(size_t)(t4 + 1) * NH]; }
        const float* evp = reinterpret_cast<const float*>(&ev);
        const float* cvp = reinterpret_cast<const float*>(&cv);
        #pragma unroll
        for (int tt = 0; tt < 4; ++tt) {
            float e = evp[tt], c = cvp[tt];
            eta = 0.36f * eta + 0.64f * ps;
            float theta = 0.5f + 1.8f * eta - c;
            memv = 0.8f * memv + e;
            float spk = (memv - theta >= 0.f) ? 1.f : 0.f;
            memv *= (1.f - spk);
            li = 0.9f * li + spk;
            ps = spk;
            int t = t4 * 4 + tt;
            if (((t >> 4) & 1) == 0) accF += li; else accS += li;
        }
        if ((t4 & 7) == 7) {
            DP[(size_t)b * 160 + h * 10 + (t4 >> 3)] = (accS - accF) * 0.0625f;
            accF = 0.f; accS = 0.f;
        }
        ev = en; cv = cn;
    }
}

// ---------------- Kernel C: fc1+fc2, 4 batch per block ----------------
__global__ void __launch_bounds__(256)
fc_kernel(const float* __restrict__ DP, const float* __restrict__ ws,
          const float* __restrict__ fc1_b, const float* __restrict__ fc2_b,
          float* __restrict__ out)
{
    __shared__ float sh_dp[4][160];
    __shared__ float mid[4][64];
    const int tid = threadIdx.x;
    const int b0 = blockIdx.x * 4;
    for (int p = tid; p < 640; p += 256) sh_dp[p / 160][p - (p / 160) * 160] = DP[(size_t)b0 * 160 + p];
    __syncthreads();
    {
        const int bl = tid >> 6, o = tid & 63;
        const float* __restrict__ fc1t = ws + OFF_FC1T;
        float z = fc1_b[o];
        for (int f = 0; f < 160; ++f) z = fmaf(sh_dp[bl][f], fc1t[f * 64 + o], z);
        mid[bl][o] = fmaxf(z, 0.f);
    }
    __syncthreads();
    if (tid < 16) {
        const int bl = tid >> 2, oo = tid & 3;
        const float* __restrict__ fc2t = ws + OFF_FC2T;
        float z = fc2_b[oo];
        #pragma unroll
        for (int jj = 0; jj < 64; ++jj) z = fmaf(mid[bl][jj], fc2t[jj * 4 + oo], z);
        out[(size_t)(b0 + bl) * 4 + oo] = z;
    }
}

// ---------------- Fallback: fused kernel (used if ws too small) ----------------
__global__ void __launch_bounds__(256, 4)
snn_fused(const float* __restrict__ xeeg, const float* __restrict__ xgeo,
          const float* __restrict__ ws,   const float* __restrict__ geo_b,
          const float* __restrict__ gamma, const float* __restrict__ fc1_b,
          const float* __restrict__ fc2_b, float* __restrict__ out)
{
    __shared__ __align__(16) float xT[NEEG][XROWS];
    __shared__ __align__(16) float h1T[NTH][64];
    __shared__ __align__(16) float h2s[64][NH];
    __shared__ __align__(16) float gms[64][NH];
    __shared__ float xg[TILE_T][NGEO];
    __shared__ float gws[NGEO*NH];
    __shared__ float dp[160];
    __shared__ float mid1[64];

    const float* __restrict__ w1t = ws + OFF_W1T;
    const float* __restrict__ b1f = ws + OFF_B1F;
    const float* __restrict__ w2t = ws + OFF_W2T;
    const float* __restrict__ b2f = ws + OFF_B2F;

    const int b = blockIdx.x, tid = threadIdx.x;
    for (int p = tid; p < NGEO*NH; p += 256) gws[p] = ws[OFF_GWT + p];

    float eta = 0.f, memv = 0.f, li = 0.f, ps = 0.f, accF = 0.f, accS = 0.f;
    float gam = 0.f;
    if (tid < NH) gam = gamma[tid];

    const int tq  = tid & 15, cq  = tid >> 4;
    const int r0a = tq * 4,   c0  = cq * 2;
    const int oq  = tid & 15, tq2 = tid >> 4;

    for (int j = 0; j < NTILES; ++j) {
        const int t0 = j * TILE_T;
        __syncthreads();
        {
            const int i = tid & 63, rbase = tid >> 6;
            const float* xb = xeeg + (size_t)b * TSEQ * NEEG + i;
            #pragma unroll
            for (int p = 0; p < 17; ++p) {
                int rx = rbase + p * 4;
                int tg = t0 - 6 + rx;
                xT[i][rx] = (tg >= 0 && tg < TSEQ) ? xb[tg * NEEG] : 0.f;
            }
        }
        for (int p = tid; p < TILE_T * NGEO; p += 256) {
            int r = p / NGEO, ii = p - r * NGEO;
            int tg = t0 + r;
            xg[r][ii] = (tg < TSEQ) ? xgeo[((size_t)b * TSEQ + tg) * NGEO + ii] : 0.f;
        }
        __syncthreads();
        {
            float acc[4][2];
            const float bbv0 = b1f[c0], bbv1 = b1f[c0 + 1];
            #pragma unroll
            for (int t = 0; t < 4; ++t) { acc[t][0] = bbv0; acc[t][1] = bbv1; }
            for (int i = 0; i < NEEG; ++i) {
                float xr[8];
                *reinterpret_cast<float4*>(&xr[0]) = *reinterpret_cast<const float4*>(&xT[i][r0a]);
                *reinterpret_cast<float4*>(&xr[4]) = *reinterpret_cast<const float4*>(&xT[i][r0a + 4]);
                #pragma unroll
                for (int k = 0; k < 5; ++k) {
                    float2 w = *reinterpret_cast<const float2*>(&w1t[(i * 5 + k) * NTH + c0]);
                    #pragma unroll
                    for (int t = 0; t < 4; ++t) {
                        acc[t][0] = fmaf(xr[t + k], w.x, acc[t][0]);
                        acc[t][1] = fmaf(xr[t + k], w.y, acc[t][1]);
                    }
                }
            }
            #pragma unroll
            for (int t = 0; t < 4; ++t) {
                int r1 = r0a + t, s = r1 - 3;
                int tg = t0 - 4 + r1;
                if (s >= 0 && s < 58) {
                    bool v = (tg >= 0 && tg < TSEQ);
                    h1T[c0][s]     = v ? fmaxf(acc[t][0], 0.f) : 0.f;
                    h1T[c0 + 1][s] = v ? fmaxf(acc[t][1], 0.f) : 0.f;
                }
            }
        }
        __syncthreads();
        if (tq2 < 14) {
            const int r0 = tq2 * 4;
            float acc2[4];
            const float bbv = b2f[oq];
            #pragma unroll
            for (int t = 0; t < 4; ++t) acc2[t] = bbv;
            for (int c = 0; c < NTH; ++c) {
                float hr[8];
                *reinterpret_cast<float4*>(&hr[0]) = *reinterpret_cast<const float4*>(&h1T[c][r0]);
                *reinterpret_cast<float4*>(&hr[4]) = *reinterpret_cast<const float4*>(&h1T[c][r0 + 4]);
                #pragma unroll
                for (int k = 0; k < 3; ++k) {
                    float wv = w2t[(c * 3 + k) * NH + oq];
                    #pragma unroll
                    for (int t = 0; t < 4; ++t) acc2[t] = fmaf(hr[t + k], wv, acc2[t]);
                }
            }
            #pragma unroll
            for (int t = 0; t < 4; ++t) h2s[r0 + t][oq] = fmaxf(acc2[t], 0.f);
        }
        for (int p = tid; p < TILE_T * NH; p += 256) {
            int r = p >> 4, hh = p & 15;
            float z = geo_b[hh];
            #pragma unroll
            for (int ii = 0; ii < NGEO; ++ii) z = fmaf(xg[r][ii], gws[ii * NH + hh], z);
            gms[r][hh] = 1.f / (1.f + expf(-z));
        }
        __syncthreads();
        if (tid < NH) {
            int nt = TSEQ - t0; if (nt > TILE_T) nt = TILE_T;
            for (int tt = 0; tt < nt; ++tt) {
                int t = t0 + tt;
                float e = h2s[tt][tid];
                float g = gms[tt][tid];
                eta = 0.36f * eta + 0.64f * ps;
                float theta = 0.5f + 1.8f * eta - gam * g;
                memv = 0.8f * memv + e;
                float spk = (memv - theta >= 0.f) ? 1.f : 0.f;
                memv *= (1.f - spk);
                li = 0.9f * li + spk;
                ps = spk;
                if (((t >> 4) & 1) == 0) accF += li; else accS += li;
                if ((t & 31) == 31) {
                    dp[tid * 10 + (t >> 5)] = (accS - accF) * 0.0625f;
                    accF = 0.f; accS = 0.f;
                }
            }
        }
    }
    __syncthreads();
    if (tid < 64) {
        const float* __restrict__ fc1t = ws + OFF_FC1T;
        float z = fc1_b[tid];
        for (int f = 0; f < 160; ++f) z = fmaf(dp[f], fc1t[f * 64 + tid], z);
        mid1[tid] = fmaxf(z, 0.f);
    }
    __syncthreads();
    if (tid < 4) {
        const float* __restrict__ fc2t = ws + OFF_FC2T;
        float z = fc2_b[tid];
        #pragma unroll
        for (int jj = 0; jj < 64; ++jj) z = fmaf(mid1[jj], fc2t[jj * 4 + tid], z);
        out[b * 4 + tid] = z;
    }
}

extern "C" void kernel_launch(void* const* d_in, const int* in_sizes, int n_in,
                              void* d_out, int out_size, void* d_ws, size_t ws_size,
                              hipStream_t stream)
{
    const float* xeeg = (const float*)d_in[0];
    const float* xgeo = (const float*)d_in[1];
    const float* c1w  = (const float*)d_in[2];
    const float* c1b  = (const float*)d_in[3];
    const float* s1   = (const float*)d_in[4];
    const float* bb1  = (const float*)d_in[5];
    const float* mm1  = (const float*)d_in[6];
    const float* vv1  = (const float*)d_in[7];
    const float* c2w  = (const float*)d_in[8];
    const float* c2b  = (const float*)d_in[9];
    const float* s2   = (const float*)d_in[10];
    const float* bb2  = (const float*)d_in[11];
    const float* mm2  = (const float*)d_in[12];
    const float* vv2  = (const float*)d_in[13];
    const float* gw   = (const float*)d_in[14];
    const float* gb   = (const float*)d_in[15];
    const float* gam  = (const float*)d_in[16];
    const float* fc1w = (const float*)d_in[17];
    const float* fc1b = (const float*)d_in[18];
    const float* fc2w = (const float*)d_in[19];
    const float* fc2b = (const float*)d_in[20];
    float* ws   = (float*)d_ws;
    float* outp = (float*)d_out;

    hipLaunchKernelGGL(prep_kernel, dim3(1), dim3(256), 0, stream,
                       c1w, c1b, s1, bb1, mm1, vv1, c2w, c2b, s2, bb2, mm2, vv2,
                       gw, fc1w, fc2w, ws);

    if (ws_size >= REQ_BYTES) {
        float* E  = ws + OFF_E;
        float* C  = ws + OFF_C;
        float* DP = ws + OFF_DP;
        hipLaunchKernelGGL(convb_kernel, dim3(TB), dim3(256), 0, stream,
                           xeeg, xgeo, ws, gb, gam, E, C);
        hipLaunchKernelGGL(scan_kernel, dim3(TB / 16), dim3(256), 0, stream,
                           E, C, DP);
        hipLaunchKernelGGL(fc_kernel, dim3(TB / 4), dim3(256), 0, stream,
                           DP, ws, fc1b, fc2b, outp);
    } else {
        hipLaunchKernelGGL(snn_fused, dim3(TB), dim3(256), 0, stream,
                           xeeg, xgeo, ws, gb, gam, fc1b, fc2b, outp);
    }
}

// Round 5
// 710.714 us; speedup vs baseline: 2.0198x; 1.2599x over previous
//
#include <hip/hip_runtime.h>
#include <math.h>

#define TB    4096
#define TSEQ  320
#define NEEG  64
#define NTH   32
#define NH    16
#define NGEO  18
#define TILE_T 64
#define NTILES 5

typedef _Float16 f16x8 __attribute__((ext_vector_type(8)));
typedef float f32x4 __attribute__((ext_vector_type(4)));
#define INV2048 4.8828125e-4f

// ws float offsets
#define OFF_W1F  0        // 10240 floats = 20480 halves: [10][2][2][64][8]
#define OFF_W2F  10240    // 1536 floats = 3072 halves:   [3][2][64][8]
#define OFF_B1   11776    // 32
#define OFF_B2   11808    // 16
#define OFF_GWT  11824    // 288  [i][h]
#define OFF_FC1T 12112    // 10240 [f][o]
#define OFF_FC2T 22352    // 256   [j][o]
#define OFF_E    32768
#define SZ_EC    (TB*TSEQ*NH)            // 20971520
#define OFF_C    (OFF_E + SZ_EC)
#define OFF_DP   (OFF_C + SZ_EC)
#define SZ_DP    (TB*160)
#define REQ_FLOATS ((size_t)OFF_DP + SZ_DP)
#define REQ_BYTES  (REQ_FLOATS * 4)      // 170,524,672

__global__ void __launch_bounds__(256)
prep_kernel(const float* __restrict__ c1w, const float* __restrict__ c1b,
            const float* __restrict__ s1,  const float* __restrict__ bb1,
            const float* __restrict__ mm1, const float* __restrict__ vv1,
            const float* __restrict__ c2w, const float* __restrict__ c2b,
            const float* __restrict__ s2,  const float* __restrict__ bb2,
            const float* __restrict__ mm2, const float* __restrict__ vv2,
            const float* __restrict__ gw,  const float* __restrict__ fc1w,
            const float* __restrict__ fc2w, float* __restrict__ ws)
{
    const int tid = threadIdx.x;
    _Float16* w1fp = reinterpret_cast<_Float16*>(ws + OFF_W1F);
    _Float16* w2fp = reinterpret_cast<_Float16*>(ws + OFF_W2F);

    // conv1 B-fragments: [kk][nb][hl][lane][j]; K = k*64 + i (i fast)
    for (int d = tid; d < 10240; d += 256) {
        int j = d & 7, l = (d >> 3) & 63, nbk = d >> 9;   // nbk = kk*2+nb
        int kk = nbk >> 1, nb = nbk & 1;
        int k = kk >> 1, i = (kk & 1) * 32 + ((l >> 4) * 8) + j;
        int c = nb * 16 + (l & 15);
        float inv = s1[c] / sqrtf(vv1[c] + 1e-5f);
        float wv = c1w[c * 320 + i * 5 + k] * inv;
        _Float16 hi = (_Float16)wv;
        _Float16 lo = (_Float16)((wv - (float)hi) * 2048.f);
        w1fp[((nbk * 2 + 0) * 64 + l) * 8 + j] = hi;
        w1fp[((nbk * 2 + 1) * 64 + l) * 8 + j] = lo;
    }
    // conv2 B-fragments: [kk2][hl][lane][j]; K = k*32 + c (c fast)
    for (int d = tid; d < 1536; d += 256) {
        int j = d & 7, l = (d >> 3) & 63, kk2 = d >> 9;
        int c = (l >> 4) * 8 + j;
        int o = l & 15;
        float inv = s2[o] / sqrtf(vv2[o] + 1e-5f);
        float wv = c2w[o * 96 + c * 3 + kk2] * inv;
        _Float16 hi = (_Float16)wv;
        _Float16 lo = (_Float16)((wv - (float)hi) * 2048.f);
        w2fp[((kk2 * 2 + 0) * 64 + l) * 8 + j] = hi;
        w2fp[((kk2 * 2 + 1) * 64 + l) * 8 + j] = lo;
    }
    if (tid < NTH) {
        float inv = s1[tid] / sqrtf(vv1[tid] + 1e-5f);
        ws[OFF_B1 + tid] = c1b[tid] * inv + bb1[tid] - mm1[tid] * inv;
    }
    if (tid < NH) {
        float inv = s2[tid] / sqrtf(vv2[tid] + 1e-5f);
        ws[OFF_B2 + tid] = c2b[tid] * inv + bb2[tid] - mm2[tid] * inv;
    }
    for (int d = tid; d < NGEO * NH; d += 256) {
        int i = d / NH, h = d - i * NH;
        ws[OFF_GWT + d] = gw[h * NGEO + i];
    }
    for (int d = tid; d < 160 * 64; d += 256) {
        int f = d / 64, o = d - f * 64;
        ws[OFF_FC1T + d] = fc1w[o * 160 + f];
    }
    if (tid < 256) {
        int j = tid / 4, o = tid - j * 4;
        ws[OFF_FC2T + tid] = fc2w[o * 64 + j];
    }
}

// ---------- Kernel A: MFMA conv1+conv2+geo, one block per batch element ----------
__global__ void __launch_bounds__(256, 2)
convm_kernel(const float* __restrict__ xeeg, const float* __restrict__ xgeo,
             const float* __restrict__ ws,   const float* __restrict__ geo_b,
             const float* __restrict__ gamma,
             float* __restrict__ E, float* __restrict__ C)
{
    __shared__ __align__(16) _Float16 w1f[10][2][2][64][8];  // 40960 B
    __shared__ __align__(16) _Float16 w2f[3][2][64][8];      // 6144 B
    __shared__ __align__(16) _Float16 xh[70 * 64];           // 8960 B
    __shared__ __align__(16) _Float16 xl[70 * 64];           // 8960 B
    __shared__ __align__(16) _Float16 h1h[66 * 32];          // 4224 B
    __shared__ __align__(16) _Float16 h1l[66 * 32];          // 4224 B
    __shared__ float xg[64][NGEO];                           // 4608 B
    __shared__ float b1s[32], b2s[16], gws[NGEO * NH], gbs[16], gams[16];

    const int b = blockIdx.x, tid = threadIdx.x;
    const int l = tid & 63, w = tid >> 6;
    const int lrow = l & 15, lkg = l >> 4;

    // ---- stage weights / constants once per block ----
    {
        const float4* src = reinterpret_cast<const float4*>(ws + OFF_W1F);
        float4* d1 = reinterpret_cast<float4*>(&w1f[0][0][0][0][0]);
        for (int p = tid; p < 2560; p += 256) d1[p] = src[p];
        const float4* s2 = reinterpret_cast<const float4*>(ws + OFF_W2F);
        float4* d2 = reinterpret_cast<float4*>(&w2f[0][0][0][0]);
        for (int p = tid; p < 384; p += 256) d2[p] = s2[p];
        if (tid < 32) b1s[tid] = ws[OFF_B1 + tid];
        if (tid < 16) {
            b2s[tid] = ws[OFF_B2 + tid];
            gbs[tid] = geo_b[tid];
            gams[tid] = gamma[tid];
        }
        for (int p = tid; p < NGEO * NH; p += 256) gws[p] = ws[OFF_GWT + p];
    }

    for (int jt = 0; jt < NTILES; ++jt) {
        const int t0 = jt * TILE_T;
        __syncthreads();   // previous tile's conv2/geo done reading h1/xg

        // ---- stage x -> fp16 hi/lo planes, XOR-swizzled (row xr=0 <-> t=t0-3) ----
        {
            const float* xb = xeeg + (size_t)b * TSEQ * NEEG;
            for (int p = tid; p < 70 * 64; p += 256) {
                int xr = p >> 6, i = p & 63;
                int tg = t0 - 3 + xr;
                float f = (tg >= 0 && tg < TSEQ) ? xb[tg * 64 + i] : 0.f;
                _Float16 hi = (_Float16)f;
                _Float16 lo = (_Float16)((f - (float)hi) * 2048.f);
                int idx = xr * 64 + (((i >> 3) ^ (xr & 7)) << 3) + (i & 7);
                xh[idx] = hi;
                xl[idx] = lo;
            }
            for (int p = tid; p < 64 * NGEO; p += 256) {
                int u = p / NGEO, ii = p - u * NGEO;
                xg[u][ii] = xgeo[((size_t)b * TSEQ + t0 + u) * NGEO + ii];
            }
        }
        __syncthreads();

        // ---- conv1 (fp16x3 MFMA): h1 rows s in [0,66), s=0 <-> t=t0-1 ----
        {
            const float bia0 = b1s[lrow], bia1 = b1s[16 + lrow];
            int mb = w;
            for (int pass = 0; pass < 2; ++pass) {
                if (pass == 1) {
                    if (w != (jt & 3)) break;
                    mb = 4;
                }
                const int mbase = mb * 16;
                int s = mbase + lrow; if (s > 65) s = 65;
                f32x4 a0h = {0.f, 0.f, 0.f, 0.f};
                f32x4 a0c = a0h, a1h = a0h, a1c = a0h;
                #pragma unroll
                for (int kk = 0; kk < 10; ++kk) {
                    const int xr = s + (kk >> 1);
                    const int gx = (kk & 1) * 4 + lkg;
                    const int off = xr * 64 + ((gx ^ (xr & 7)) << 3);
                    f16x8 Ah = *reinterpret_cast<const f16x8*>(&xh[off]);
                    f16x8 Al = *reinterpret_cast<const f16x8*>(&xl[off]);
                    f16x8 B0h = *reinterpret_cast<const f16x8*>(&w1f[kk][0][0][l][0]);
                    f16x8 B0l = *reinterpret_cast<const f16x8*>(&w1f[kk][0][1][l][0]);
                    f16x8 B1h = *reinterpret_cast<const f16x8*>(&w1f[kk][1][0][l][0]);
                    f16x8 B1l = *reinterpret_cast<const f16x8*>(&w1f[kk][1][1][l][0]);
                    a0h = __builtin_amdgcn_mfma_f32_16x16x32_f16(Ah, B0h, a0h, 0, 0, 0);
                    a0c = __builtin_amdgcn_mfma_f32_16x16x32_f16(Ah, B0l, a0c, 0, 0, 0);
                    a0c = __builtin_amdgcn_mfma_f32_16x16x32_f16(Al, B0h, a0c, 0, 0, 0);
                    a1h = __builtin_amdgcn_mfma_f32_16x16x32_f16(Ah, B1h, a1h, 0, 0, 0);
                    a1c = __builtin_amdgcn_mfma_f32_16x16x32_f16(Ah, B1l, a1c, 0, 0, 0);
                    a1c = __builtin_amdgcn_mfma_f32_16x16x32_f16(Al, B1h, a1c, 0, 0, 0);
                }
                #pragma unroll
                for (int r = 0; r < 4; ++r) {
                    int so = mbase + lkg * 4 + r;
                    if (so < 66) {
                        int tg = t0 - 1 + so;
                        bool v = (tg >= 0 && tg < TSEQ);
                        float v0 = v ? fmaxf(fmaf(a0c[r], INV2048, a0h[r]) + bia0, 0.f) : 0.f;
                        float v1 = v ? fmaxf(fmaf(a1c[r], INV2048, a1h[r]) + bia1, 0.f) : 0.f;
                        int key = (so >> 1) & 3;
                        int g0 = (lrow >> 3) ^ key;
                        int g1 = (2 + (lrow >> 3)) ^ key;
                        int i0 = so * 32 + (g0 << 3) + (lrow & 7);
                        int i1 = so * 32 + (g1 << 3) + (lrow & 7);
                        _Float16 h0 = (_Float16)v0;
                        _Float16 h1v = (_Float16)v1;
                        h1h[i0] = h0; h1l[i0] = (_Float16)((v0 - (float)h0) * 2048.f);
                        h1h[i1] = h1v; h1l[i1] = (_Float16)((v1 - (float)h1v) * 2048.f);
                    }
                }
            }
        }
        __syncthreads();

        // ---- conv2 (fp16x3 MFMA) -> E[b][h][t] ----
        {
            const int ub = w * 16;
            f32x4 ah = {0.f, 0.f, 0.f, 0.f};
            f32x4 ac = ah;
            #pragma unroll
            for (int kk = 0; kk < 3; ++kk) {
                int srow = ub + lrow + kk;
                int off = srow * 32 + ((lkg ^ ((srow >> 1) & 3)) << 3);
                f16x8 Ah = *reinterpret_cast<const f16x8*>(&h1h[off]);
                f16x8 Al = *reinterpret_cast<const f16x8*>(&h1l[off]);
                f16x8 Bh = *reinterpret_cast<const f16x8*>(&w2f[kk][0][l][0]);
                f16x8 Bl = *reinterpret_cast<const f16x8*>(&w2f[kk][1][l][0]);
                ah = __builtin_amdgcn_mfma_f32_16x16x32_f16(Ah, Bh, ah, 0, 0, 0);
                ac = __builtin_amdgcn_mfma_f32_16x16x32_f16(Ah, Bl, ac, 0, 0, 0);
                ac = __builtin_amdgcn_mfma_f32_16x16x32_f16(Al, Bh, ac, 0, 0, 0);
            }
            const float bia = b2s[lrow];
            float4 ev;
            float* evp = reinterpret_cast<float*>(&ev);
            #pragma unroll
            for (int r = 0; r < 4; ++r)
                evp[r] = fmaxf(fmaf(ac[r], INV2048, ah[r]) + bia, 0.f);
            float* ep = E + ((size_t)b * 16 + lrow) * TSEQ + t0 + ub + lkg * 4;
            *reinterpret_cast<float4*>(ep) = ev;
        }
        // ---- geo modulation (fp32) -> C[b][h][t] ----
        {
            const int hh = tid & 15, uq = tid >> 4;
            const float gam = gams[hh], gb = gbs[hh];
            float4 cv;
            float* cvp = reinterpret_cast<float*>(&cv);
            #pragma unroll
            for (int tt = 0; tt < 4; ++tt) {
                int u = uq * 4 + tt;
                float z = gb;
                #pragma unroll
                for (int ii = 0; ii < NGEO; ++ii)
                    z = fmaf(xg[u][ii], gws[ii * NH + hh], z);
                cvp[tt] = gam * (1.f / (1.f + expf(-z)));
            }
            float* cp = C + ((size_t)b * 16 + hh) * TSEQ + t0 + uq * 4;
            *reinterpret_cast<float4*>(cp) = cv;
        }
    }
}

// ---------- Kernel B: ALIF scan, one lane per (b,h) ----------
__global__ void __launch_bounds__(256)
scan_kernel(const float* __restrict__ E, const float* __restrict__ C,
            float* __restrict__ DP)
{
    const int tid = threadIdx.x;
    const int h = tid & 15;
    const int b = blockIdx.x * 16 + (tid >> 4);
    const float4* e4 = reinterpret_cast<const float4*>(E) + ((size_t)b * 16 + h) * 80;
    const float4* c4 = reinterpret_cast<const float4*>(C) + ((size_t)b * 16 + h) * 80;

    float eta = 0.f, memv = 0.f, li = 0.f, ps = 0.f, accF = 0.f, accS = 0.f;
    float4 ev = e4[0], cv = c4[0];
    for (int t4 = 0; t4 < 80; ++t4) {
        float4 en, cn;
        if (t4 < 79) { en = e4[t4 + 1]; cn = c4[t4 + 1]; }
        const float* evp = reinterpret_cast<const float*>(&ev);
        const float* cvp = reinterpret_cast<const float*>(&cv);
        #pragma unroll
        for (int tt = 0; tt < 4; ++tt) {
            float e = evp[tt], c = cvp[tt];
            eta = 0.36f * eta + 0.64f * ps;
            float theta = 0.5f + 1.8f * eta - c;
            memv = 0.8f * memv + e;
            float spk = (memv - theta >= 0.f) ? 1.f : 0.f;
            memv *= (1.f - spk);
            li = 0.9f * li + spk;
            ps = spk;
            int t = t4 * 4 + tt;
            if (((t >> 4) & 1) == 0) accF += li; else accS += li;
        }
        if ((t4 & 7) == 7) {
            DP[(size_t)b * 160 + h * 10 + (t4 >> 3)] = (accS - accF) * 0.0625f;
            accF = 0.f; accS = 0.f;
        }
        ev = en; cv = cn;
    }
}

// ---------- Kernel C: fc1+fc2, 4 batch per block ----------
__global__ void __launch_bounds__(256)
fc_kernel(const float* __restrict__ DP, const float* __restrict__ ws,
          const float* __restrict__ fc1_b, const float* __restrict__ fc2_b,
          float* __restrict__ out)
{
    __shared__ float sh_dp[4][160];
    __shared__ float mid[4][64];
    const int tid = threadIdx.x;
    const int b0 = blockIdx.x * 4;
    for (int p = tid; p < 640; p += 256)
        sh_dp[p / 160][p - (p / 160) * 160] = DP[(size_t)b0 * 160 + p];
    __syncthreads();
    {
        const int bl = tid >> 6, o = tid & 63;
        const float* __restrict__ fc1t = ws + OFF_FC1T;
        float z = fc1_b[o];
        for (int f = 0; f < 160; ++f) z = fmaf(sh_dp[bl][f], fc1t[f * 64 + o], z);
        mid[bl][o] = fmaxf(z, 0.f);
    }
    __syncthreads();
    if (tid < 16) {
        const int bl = tid >> 2, oo = tid & 3;
        const float* __restrict__ fc2t = ws + OFF_FC2T;
        float z = fc2_b[oo];
        #pragma unroll
        for (int jj = 0; jj < 64; ++jj) z = fmaf(mid[bl][jj], fc2t[jj * 4 + oo], z);
        out[(size_t)(b0 + bl) * 4 + oo] = z;
    }
}

extern "C" void kernel_launch(void* const* d_in, const int* in_sizes, int n_in,
                              void* d_out, int out_size, void* d_ws, size_t ws_size,
                              hipStream_t stream)
{
    const float* xeeg = (const float*)d_in[0];
    const float* xgeo = (const float*)d_in[1];
    const float* c1w  = (const float*)d_in[2];
    const float* c1b  = (const float*)d_in[3];
    const float* s1   = (const float*)d_in[4];
    const float* bb1  = (const float*)d_in[5];
    const float* mm1  = (const float*)d_in[6];
    const float* vv1  = (const float*)d_in[7];
    const float* c2w  = (const float*)d_in[8];
    const float* c2b  = (const float*)d_in[9];
    const float* s2   = (const float*)d_in[10];
    const float* bb2  = (const float*)d_in[11];
    const float* mm2  = (const float*)d_in[12];
    const float* vv2  = (const float*)d_in[13];
    const float* gw   = (const float*)d_in[14];
    const float* gb   = (const float*)d_in[15];
    const float* gam  = (const float*)d_in[16];
    const float* fc1w = (const float*)d_in[17];
    const float* fc1b = (const float*)d_in[18];
    const float* fc2w = (const float*)d_in[19];
    const float* fc2b = (const float*)d_in[20];
    float* ws   = (float*)d_ws;
    float* outp = (float*)d_out;

    hipLaunchKernelGGL(prep_kernel, dim3(1), dim3(256), 0, stream,
                       c1w, c1b, s1, bb1, mm1, vv1, c2w, c2b, s2, bb2, mm2, vv2,
                       gw, fc1w, fc2w, ws);

    float* E  = ws + OFF_E;
    float* C  = ws + OFF_C;
    float* DP = ws + OFF_DP;
    hipLaunchKernelGGL(convm_kernel, dim3(TB), dim3(256), 0, stream,
                       xeeg, xgeo, ws, gb, gam, E, C);
    hipLaunchKernelGGL(scan_kernel, dim3(TB / 16), dim3(256), 0, stream,
                       E, C, DP);
    hipLaunchKernelGGL(fc_kernel, dim3(TB / 4), dim3(256), 0, stream,
                       DP, ws, fc1b, fc2b, outp);
}

// Round 6
// 621.847 us; speedup vs baseline: 2.3085x; 1.1429x over previous
//
#include <hip/hip_runtime.h>
#include <math.h>

#define TB    4096
#define TSEQ  320
#define NEEG  64
#define NTH   32
#define NH    16
#define NGEO  18
#define TILE_T 64
#define NTILES 5

typedef _Float16 f16x8 __attribute__((ext_vector_type(8)));
typedef _Float16 f16x2 __attribute__((ext_vector_type(2)));
typedef float f32x4 __attribute__((ext_vector_type(4)));
#define INV2048 4.8828125e-4f

// ws float offsets
#define OFF_W1F  0        // 10240 floats = 20480 halves: [kk][nb][hl][64][8]
#define OFF_W2F  10240    // 1536 floats = 3072 halves:   [kk2][hl][64][8]
#define OFF_B1   11776    // 32
#define OFF_B2   11808    // 16
#define OFF_GWT  11824    // 288  [i][h]
#define OFF_FC1T 12112    // 10240 [f][o]
#define OFF_FC2T 22352    // 256   [j][o]
#define OFF_E    32768
#define SZ_EC    (TB*TSEQ*NH)            // 20971520
#define OFF_C    (OFF_E + SZ_EC)
#define OFF_DP   (OFF_C + SZ_EC)
#define SZ_DP    (TB*160)
#define REQ_FLOATS ((size_t)OFF_DP + SZ_DP)
#define REQ_BYTES  (REQ_FLOATS * 4)      // 170,524,672

__global__ void __launch_bounds__(256)
prep_kernel(const float* __restrict__ c1w, const float* __restrict__ c1b,
            const float* __restrict__ s1,  const float* __restrict__ bb1,
            const float* __restrict__ mm1, const float* __restrict__ vv1,
            const float* __restrict__ c2w, const float* __restrict__ c2b,
            const float* __restrict__ s2,  const float* __restrict__ bb2,
            const float* __restrict__ mm2, const float* __restrict__ vv2,
            const float* __restrict__ gw,  const float* __restrict__ fc1w,
            const float* __restrict__ fc2w, float* __restrict__ ws)
{
    const int tid = threadIdx.x;
    _Float16* w1fp = reinterpret_cast<_Float16*>(ws + OFF_W1F);
    _Float16* w2fp = reinterpret_cast<_Float16*>(ws + OFF_W2F);

    // conv1 B-fragments: [kk][nb][hl][lane][j]; K = k*64 + i (i fast)
    for (int d = tid; d < 10240; d += 256) {
        int j = d & 7, l = (d >> 3) & 63, nbk = d >> 9;   // nbk = kk*2+nb
        int kk = nbk >> 1, nb = nbk & 1;
        int k = kk >> 1, i = (kk & 1) * 32 + ((l >> 4) * 8) + j;
        int c = nb * 16 + (l & 15);
        float inv = s1[c] / sqrtf(vv1[c] + 1e-5f);
        float wv = c1w[c * 320 + i * 5 + k] * inv;
        _Float16 hi = (_Float16)wv;
        _Float16 lo = (_Float16)((wv - (float)hi) * 2048.f);
        w1fp[((nbk * 2 + 0) * 64 + l) * 8 + j] = hi;
        w1fp[((nbk * 2 + 1) * 64 + l) * 8 + j] = lo;
    }
    // conv2 B-fragments: [kk2][hl][lane][j]; K = k*32 + c (c fast)
    for (int d = tid; d < 1536; d += 256) {
        int j = d & 7, l = (d >> 3) & 63, kk2 = d >> 9;
        int c = (l >> 4) * 8 + j;
        int o = l & 15;
        float inv = s2[o] / sqrtf(vv2[o] + 1e-5f);
        float wv = c2w[o * 96 + c * 3 + kk2] * inv;
        _Float16 hi = (_Float16)wv;
        _Float16 lo = (_Float16)((wv - (float)hi) * 2048.f);
        w2fp[((kk2 * 2 + 0) * 64 + l) * 8 + j] = hi;
        w2fp[((kk2 * 2 + 1) * 64 + l) * 8 + j] = lo;
    }
    if (tid < NTH) {
        float inv = s1[tid] / sqrtf(vv1[tid] + 1e-5f);
        ws[OFF_B1 + tid] = c1b[tid] * inv + bb1[tid] - mm1[tid] * inv;
    }
    if (tid < NH) {
        float inv = s2[tid] / sqrtf(vv2[tid] + 1e-5f);
        ws[OFF_B2 + tid] = c2b[tid] * inv + bb2[tid] - mm2[tid] * inv;
    }
    for (int d = tid; d < NGEO * NH; d += 256) {
        int i = d / NH, h = d - i * NH;
        ws[OFF_GWT + d] = gw[h * NGEO + i];
    }
    for (int d = tid; d < 160 * 64; d += 256) {
        int f = d / 64, o = d - f * 64;
        ws[OFF_FC1T + d] = fc1w[o * 160 + f];
    }
    if (tid < 256) {
        int j = tid / 4, o = tid - j * 4;
        ws[OFF_FC2T + tid] = fc2w[o * 64 + j];
    }
}

// ---------- Kernel A: MFMA conv1+conv2+geo; w1 B-frags register-resident ----------
__global__ void __launch_bounds__(256, 4)
convm_kernel(const float* __restrict__ xeeg, const float* __restrict__ xgeo,
             const float* __restrict__ ws,   const float* __restrict__ geo_b,
             const float* __restrict__ gamma,
             float* __restrict__ E, float* __restrict__ C)
{
    __shared__ __align__(16) _Float16 w2f[3][2][64][8];      // 6144 B
    __shared__ __align__(16) _Float16 xh[70 * 64];           // 8960 B
    __shared__ __align__(16) _Float16 xl[70 * 64];           // 8960 B
    __shared__ __align__(16) _Float16 h1h[66 * 32];          // 4224 B
    __shared__ __align__(16) _Float16 h1l[66 * 32];          // 4224 B
    __shared__ float xg[64][NGEO];                           // 4608 B
    __shared__ float b1s[32], b2s[16], gws[NGEO * NH], gbs[16], gams[16];
    // total ~37.7 KB -> 4 blocks/CU

    const int b = blockIdx.x, tid = threadIdx.x;
    const int l = tid & 63, w = tid >> 6;
    const int lrow = l & 15, lkg = l >> 4;
    const int nb = w >> 1, wsub = w & 1;   // conv1: wave pair per output-channel half

    // ---- conv1 B-fragments -> registers (per-wave nb half) ----
    f16x8 B1h[10], B1l[10];
    {
        const f16x8* wsrc = reinterpret_cast<const f16x8*>(ws + OFF_W1F);
        #pragma unroll
        for (int kk = 0; kk < 10; ++kk) {
            B1h[kk] = wsrc[((kk * 2 + nb) * 2 + 0) * 64 + l];
            B1l[kk] = wsrc[((kk * 2 + nb) * 2 + 1) * 64 + l];
        }
    }
    // ---- stage w2 + constants into LDS ----
    {
        const float4* s2 = reinterpret_cast<const float4*>(ws + OFF_W2F);
        float4* d2 = reinterpret_cast<float4*>(&w2f[0][0][0][0]);
        for (int p = tid; p < 384; p += 256) d2[p] = s2[p];
        if (tid < 32) b1s[tid] = ws[OFF_B1 + tid];
        if (tid < 16) {
            b2s[tid] = ws[OFF_B2 + tid];
            gbs[tid] = geo_b[tid];
            gams[tid] = gamma[tid];
        }
        for (int p = tid; p < NGEO * NH; p += 256) gws[p] = ws[OFF_GWT + p];
    }

    for (int jt = 0; jt < NTILES; ++jt) {
        const int t0 = jt * TILE_T;
        __syncthreads();   // previous tile's consumers done with xh/xl/h1/xg

        // ---- stage x -> fp16 hi/lo planes, XOR-swizzled; row xr=0 <-> t=t0-3 ----
        {
            const float* xb = xeeg + (size_t)b * TSEQ * NEEG;
            for (int p = tid; p < 70 * 32; p += 256) {
                int xr = p >> 5, ip = (p & 31) * 2;     // i = ip, ip+1 (same 8-group)
                int tg = t0 - 3 + xr;
                float2 f2 = (tg >= 0 && tg < TSEQ)
                          ? *reinterpret_cast<const float2*>(&xb[tg * 64 + ip])
                          : make_float2(0.f, 0.f);
                _Float16 h0 = (_Float16)f2.x, h1v = (_Float16)f2.y;
                f16x2 vh = {h0, h1v};
                f16x2 vl = {(_Float16)((f2.x - (float)h0) * 2048.f),
                            (_Float16)((f2.y - (float)h1v) * 2048.f)};
                int idx = xr * 64 + (((ip >> 3) ^ (xr & 7)) << 3) + (ip & 7);
                *reinterpret_cast<f16x2*>(&xh[idx]) = vh;
                *reinterpret_cast<f16x2*>(&xl[idx]) = vl;
            }
            for (int p = tid; p < 64 * NGEO; p += 256) {
                int u = p / NGEO, ii = p - u * NGEO;
                xg[u][ii] = xgeo[((size_t)b * TSEQ + t0 + u) * NGEO + ii];
            }
        }
        __syncthreads();

        // ---- conv1 (fp16x3 MFMA, 3 indep accum chains): h1 rows s in [0,66) ----
        {
            const float bia = b1s[nb * 16 + lrow];
            #pragma unroll
            for (int pi = 0; pi < 3; ++pi) {
                const int mb = wsub + pi * 2;           // wsub0: 0,2,4; wsub1: 1,3
                if (mb > 4) break;
                const int mbase = mb * 16;
                int s = mbase + lrow; if (s > 65) s = 65;
                f32x4 aH = {0.f, 0.f, 0.f, 0.f};
                f32x4 aM = aH, aL = aH;
                #pragma unroll
                for (int kk = 0; kk < 10; ++kk) {
                    const int xr = s + (kk >> 1);
                    const int gx = (kk & 1) * 4 + lkg;
                    const int off = xr * 64 + ((gx ^ (xr & 7)) << 3);
                    f16x8 Ah = *reinterpret_cast<const f16x8*>(&xh[off]);
                    f16x8 Al = *reinterpret_cast<const f16x8*>(&xl[off]);
                    aH = __builtin_amdgcn_mfma_f32_16x16x32_f16(Ah, B1h[kk], aH, 0, 0, 0);
                    aM = __builtin_amdgcn_mfma_f32_16x16x32_f16(Ah, B1l[kk], aM, 0, 0, 0);
                    aL = __builtin_amdgcn_mfma_f32_16x16x32_f16(Al, B1h[kk], aL, 0, 0, 0);
                }
                #pragma unroll
                for (int r = 0; r < 4; ++r) {
                    int so = mbase + lkg * 4 + r;
                    if (so < 66) {
                        int tg = t0 - 1 + so;
                        bool v = (tg >= 0 && tg < TSEQ);
                        float val = v ? fmaxf(fmaf(aM[r] + aL[r], INV2048, aH[r]) + bia, 0.f) : 0.f;
                        int key = (so >> 1) & 3;
                        int g = (nb * 2 + (lrow >> 3)) ^ key;
                        int idx = so * 32 + (g << 3) + (lrow & 7);
                        _Float16 hh = (_Float16)val;
                        h1h[idx] = hh;
                        h1l[idx] = (_Float16)((val - (float)hh) * 2048.f);
                    }
                }
            }
        }
        __syncthreads();

        // ---- conv2 (fp16x3 MFMA) -> E[b][h][t] ----
        {
            const int ub = w * 16;
            f32x4 aH = {0.f, 0.f, 0.f, 0.f};
            f32x4 aM = aH, aL = aH;
            #pragma unroll
            for (int kk = 0; kk < 3; ++kk) {
                int srow = ub + lrow + kk;
                int off = srow * 32 + ((lkg ^ ((srow >> 1) & 3)) << 3);
                f16x8 Ah = *reinterpret_cast<const f16x8*>(&h1h[off]);
                f16x8 Al = *reinterpret_cast<const f16x8*>(&h1l[off]);
                f16x8 Bh = *reinterpret_cast<const f16x8*>(&w2f[kk][0][l][0]);
                f16x8 Bl = *reinterpret_cast<const f16x8*>(&w2f[kk][1][l][0]);
                aH = __builtin_amdgcn_mfma_f32_16x16x32_f16(Ah, Bh, aH, 0, 0, 0);
                aM = __builtin_amdgcn_mfma_f32_16x16x32_f16(Ah, Bl, aM, 0, 0, 0);
                aL = __builtin_amdgcn_mfma_f32_16x16x32_f16(Al, Bh, aL, 0, 0, 0);
            }
            const float bia = b2s[lrow];
            float4 ev;
            float* evp = reinterpret_cast<float*>(&ev);
            #pragma unroll
            for (int r = 0; r < 4; ++r)
                evp[r] = fmaxf(fmaf(aM[r] + aL[r], INV2048, aH[r]) + bia, 0.f);
            float* ep = E + ((size_t)b * 16 + lrow) * TSEQ + t0 + ub + lkg * 4;
            *reinterpret_cast<float4*>(ep) = ev;
        }
        // ---- geo modulation (fp32) -> C[b][h][t] ----
        {
            const int hh = tid & 15, uq = tid >> 4;
            const float gam = gams[hh], gb = gbs[hh];
            float4 cv;
            float* cvp = reinterpret_cast<float*>(&cv);
            #pragma unroll
            for (int tt = 0; tt < 4; ++tt) {
                int u = uq * 4 + tt;
                float z = gb;
                #pragma unroll
                for (int ii = 0; ii < NGEO; ++ii)
                    z = fmaf(xg[u][ii], gws[ii * NH + hh], z);
                cvp[tt] = gam * (1.f / (1.f + expf(-z)));
            }
            float* cp = C + ((size_t)b * 16 + hh) * TSEQ + t0 + uq * 4;
            *reinterpret_cast<float4*>(cp) = cv;
        }
    }
}

// ---------- Kernel B: ALIF scan, one lane per (b,h) ----------
__global__ void __launch_bounds__(256)
scan_kernel(const float* __restrict__ E, const float* __restrict__ C,
            float* __restrict__ DP)
{
    const int tid = threadIdx.x;
    const int h = tid & 15;
    const int b = blockIdx.x * 16 + (tid >> 4);
    const float4* e4 = reinterpret_cast<const float4*>(E) + ((size_t)b * 16 + h) * 80;
    const float4* c4 = reinterpret_cast<const float4*>(C) + ((size_t)b * 16 + h) * 80;

    float eta = 0.f, memv = 0.f, li = 0.f, ps = 0.f, accF = 0.f, accS = 0.f;
    float4 ev = e4[0], cv = c4[0];
    for (int t4 = 0; t4 < 80; ++t4) {
        float4 en, cn;
        if (t4 < 79) { en = e4[t4 + 1]; cn = c4[t4 + 1]; }
        const float* evp = reinterpret_cast<const float*>(&ev);
        const float* cvp = reinterpret_cast<const float*>(&cv);
        #pragma unroll
        for (int tt = 0; tt < 4; ++tt) {
            float e = evp[tt], c = cvp[tt];
            eta = 0.36f * eta + 0.64f * ps;
            float theta = 0.5f + 1.8f * eta - c;
            memv = 0.8f * memv + e;
            float spk = (memv - theta >= 0.f) ? 1.f : 0.f;
            memv *= (1.f - spk);
            li = 0.9f * li + spk;
            ps = spk;
            int t = t4 * 4 + tt;
            if (((t >> 4) & 1) == 0) accF += li; else accS += li;
        }
        if ((t4 & 7) == 7) {
            DP[(size_t)b * 160 + h * 10 + (t4 >> 3)] = (accS - accF) * 0.0625f;
            accF = 0.f; accS = 0.f;
        }
        ev = en; cv = cn;
    }
}

// ---------- Kernel C: fc1+fc2, 4 batch per block ----------
__global__ void __launch_bounds__(256)
fc_kernel(const float* __restrict__ DP, const float* __restrict__ ws,
          const float* __restrict__ fc1_b, const float* __restrict__ fc2_b,
          float* __restrict__ out)
{
    __shared__ float sh_dp[4][160];
    __shared__ float mid[4][64];
    const int tid = threadIdx.x;
    const int b0 = blockIdx.x * 4;
    for (int p = tid; p < 640; p += 256)
        sh_dp[p / 160][p - (p / 160) * 160] = DP[(size_t)b0 * 160 + p];
    __syncthreads();
    {
        const int bl = tid >> 6, o = tid & 63;
        const float* __restrict__ fc1t = ws + OFF_FC1T;
        float z = fc1_b[o];
        for (int f = 0; f < 160; ++f) z = fmaf(sh_dp[bl][f], fc1t[f * 64 + o], z);
        mid[bl][o] = fmaxf(z, 0.f);
    }
    __syncthreads();
    if (tid < 16) {
        const int bl = tid >> 2, oo = tid & 3;
        const float* __restrict__ fc2t = ws + OFF_FC2T;
        float z = fc2_b[oo];
        #pragma unroll
        for (int jj = 0; jj < 64; ++jj) z = fmaf(mid[bl][jj], fc2t[jj * 4 + oo], z);
        out[(size_t)(b0 + bl) * 4 + oo] = z;
    }
}

extern "C" void kernel_launch(void* const* d_in, const int* in_sizes, int n_in,
                              void* d_out, int out_size, void* d_ws, size_t ws_size,
                              hipStream_t stream)
{
    const float* xeeg = (const float*)d_in[0];
    const float* xgeo = (const float*)d_in[1];
    const float* c1w  = (const float*)d_in[2];
    const float* c1b  = (const float*)d_in[3];
    const float* s1   = (const float*)d_in[4];
    const float* bb1  = (const float*)d_in[5];
    const float* mm1  = (const float*)d_in[6];
    const float* vv1  = (const float*)d_in[7];
    const float* c2w  = (const float*)d_in[8];
    const float* c2b  = (const float*)d_in[9];
    const float* s2   = (const float*)d_in[10];
    const float* bb2  = (const float*)d_in[11];
    const float* mm2  = (const float*)d_in[12];
    const float* vv2  = (const float*)d_in[13];
    const float* gw   = (const float*)d_in[14];
    const float* gb   = (const float*)d_in[15];
    const float* gam  = (const float*)d_in[16];
    const float* fc1w = (const float*)d_in[17];
    const float* fc1b = (const float*)d_in[18];
    const float* fc2w = (const float*)d_in[19];
    const float* fc2b = (const float*)d_in[20];
    float* ws   = (float*)d_ws;
    float* outp = (float*)d_out;

    hipLaunchKernelGGL(prep_kernel, dim3(1), dim3(256), 0, stream,
                       c1w, c1b, s1, bb1, mm1, vv1, c2w, c2b, s2, bb2, mm2, vv2,
                       gw, fc1w, fc2w, ws);

    float* E  = ws + OFF_E;
    float* C  = ws + OFF_C;
    float* DP = ws + OFF_DP;
    hipLaunchKernelGGL(convm_kernel, dim3(TB), dim3(256), 0, stream,
                       xeeg, xgeo, ws, gb, gam, E, C);
    hipLaunchKernelGGL(scan_kernel, dim3(TB / 16), dim3(256), 0, stream,
                       E, C, DP);
    hipLaunchKernelGGL(fc_kernel, dim3(TB / 4), dim3(256), 0, stream,
                       DP, ws, fc1b, fc2b, outp);
}